// Round 4
// baseline (485.430 us; speedup 1.0000x reference)
//
#include <hip/hip_runtime.h>
#include <math.h>

// FeatureWeightNet: grid_sample(bilinear,border) -> group correlation (G=8) ->
// MLP(8->16->8->1) with per-batch BN stats -> sigmoid.
// R4: 6 plain dispatches (cooperative launch failed silently in R3 — never
// again without a verified path):
//   k_transpose  NCHW fp32 -> NHWC bf16
//   k_sample     gather + correlation + fused BN1-stats partials
//   k_fin1       16 blocks, one BN1 channel each
//   k_stats2     512 blocks, BN2 partials
//   k_fin2       8 blocks, one BN2 channel each
//   k_final      epilogue MLP + sigmoid

constexpr int   Bc  = 2;
constexpr int   Cc  = 64;
constexpr int   Hc  = 256;
constexpr int   Wc  = 320;
constexpr int   NBc = 9;
constexpr int   HWc = Hc * Wc;            // 81920
constexpr int   NPIX = Bc * HWc;          // 163840
constexpr int   NPT  = Bc * NBc * HWc;    // 1474560 (= out_size)
constexpr float EPSV = 1e-5f;

constexpr int NBLK_S = NPIX / 32;         // 5120 sample blocks
constexpr int NB2    = 512;               // stats2 partial blocks

// workspace layout in float units (~69 MB)
constexpr size_t OFF_FEATB = 0;                               // NHWC bf16: NPIX*64 ushort
constexpr size_t OFF_S     = OFF_FEATB + (size_t)NPIX * 32;   // s: NPT*8 fp32
constexpr size_t OFF_PT    = OFF_S + (size_t)NPT * 8;         // pT[32][NBLK_S]
constexpr size_t OFF_BN1   = OFF_PT + (size_t)32 * NBLK_S;    // a1[16], c1[16]
constexpr size_t OFF_P2T   = OFF_BN1 + 32;                    // p2T[16][NB2]
constexpr size_t OFF_BN2   = OFF_P2T + (size_t)16 * NB2;      // a2[8], c2[8]

__device__ __forceinline__ unsigned short f2bf_rne(float v) {
  unsigned int u = __float_as_uint(v);
  unsigned int r = (u + 0x7fffu + ((u >> 16) & 1u)) >> 16;
  return (unsigned short)r;
}

__device__ __forceinline__ void unpack8(uint4 u, float f[8]) {
  f[0] = __uint_as_float(u.x << 16);
  f[1] = __uint_as_float(u.x & 0xffff0000u);
  f[2] = __uint_as_float(u.y << 16);
  f[3] = __uint_as_float(u.y & 0xffff0000u);
  f[4] = __uint_as_float(u.z << 16);
  f[5] = __uint_as_float(u.z & 0xffff0000u);
  f[6] = __uint_as_float(u.w << 16);
  f[7] = __uint_as_float(u.w & 0xffff0000u);
}

// ---------------------------------------------------------------------------
// K0: NCHW fp32 -> NHWC bf16 transpose of ref_feature (64 ch).
__global__ __launch_bounds__(256) void k_transpose(
    const float* __restrict__ feat, unsigned short* __restrict__ featB) {
  __shared__ float lds[64][65];
  const int tid  = threadIdx.x;
  const int b    = blockIdx.x / (HWc / 64);
  const int tile = blockIdx.x % (HWc / 64);
  const int hw0  = tile * 64;
  const int p    = tid & 63;
  const int ty   = tid >> 6;  // 0..3

  const float* src = feat + (size_t)b * Cc * HWc + hw0 + p;
#pragma unroll
  for (int c0 = 0; c0 < 64; c0 += 4) {
    lds[c0 + ty][p] = src[(size_t)(c0 + ty) * HWc];
  }
  __syncthreads();
  const int ch = tid & 63;
  unsigned short* dst = featB + ((size_t)b * HWc + hw0) * 64 + ch;
#pragma unroll
  for (int p0 = 0; p0 < 64; p0 += 4) {
    dst[(size_t)(p0 + ty) * 64] = f2bf_rne(lds[ch][p0 + ty]);
  }
}

// ---------------------------------------------------------------------------
// K1: grid sample + group correlation + fused BN1-stats partials.
// 8 lanes per pixel; lane j owns group j (16 B bf16 per tap). Block = 32 px.
__global__ __launch_bounds__(256, 6) void k_sample(
    const float* __restrict__ grid, const unsigned short* __restrict__ featB,
    const float* __restrict__ w0, float* __restrict__ sOut,
    float* __restrict__ pT) {
  __shared__ float sL[288 * 9];   // [point][j], stride 9 kills 8-stride conflicts
  __shared__ float w0s[128];
  __shared__ float red[4 * 32];
  const int tid = threadIdx.x;
  const int pix = tid >> 3;                      // 0..31 cluster in block
  const int cid = blockIdx.x * 32 + pix;         // pixel id in [0, NPIX)
  const int j   = tid & 7;                       // group
  const int b   = cid / HWc;
  const int hw  = cid - b * HWc;
  const int h   = hw / Wc;
  const int w   = hw - h * Wc;

  if (tid < 128) w0s[tid] = w0[tid];

  // ref vector (bf16) from own NHWC record: one coalesced uint4 per lane
  const uint4* fbAll = (const uint4*)featB;
  const uint4 ur = fbAll[(size_t)cid * 8 + j];
  float r[8];
  unpack8(ur, r);

  const uint4* fb = fbAll + (size_t)b * HWc * 8;

#pragma unroll 3
  for (int n = 0; n < NBc; ++n) {
    const size_t gi = ((((size_t)b * NBc + n) * Hc + h) * Wc + w) * 2;
    const float2 g2 = *(const float2*)(grid + gi);
    float ix = ((g2.x + 1.f) * (float)Wc - 1.f) * 0.5f;
    float iy = ((g2.y + 1.f) * (float)Hc - 1.f) * 0.5f;
    ix = fminf(fmaxf(ix, 0.f), (float)(Wc - 1));
    iy = fminf(fmaxf(iy, 0.f), (float)(Hc - 1));
    const float x0f = floorf(ix), y0f = floorf(iy);
    const float fx = ix - x0f, fy = iy - y0f;
    const int x0 = (int)x0f, y0 = (int)y0f;
    const int x1 = min(x0 + 1, Wc - 1), y1 = min(y0 + 1, Hc - 1);
    const float w00 = (1.f - fx) * (1.f - fy);
    const float w01 = fx * (1.f - fy);
    const float w10 = (1.f - fx) * fy;
    const float w11 = fx * fy;

    const uint4 u00 = fb[(size_t)(y0 * Wc + x0) * 8 + j];
    const uint4 u01 = fb[(size_t)(y0 * Wc + x1) * 8 + j];
    const uint4 u10 = fb[(size_t)(y1 * Wc + x0) * 8 + j];
    const uint4 u11 = fb[(size_t)(y1 * Wc + x1) * 8 + j];
    float a[8], c[8], d[8], e[8];
    unpack8(u00, a);
    unpack8(u01, c);
    unpack8(u10, d);
    unpack8(u11, e);

    float s = 0.f;
#pragma unroll
    for (int k = 0; k < 8; ++k) {
      s += (w00 * a[k] + w01 * c[k] + w10 * d[k] + w11 * e[k]) * r[k];
    }
    s *= 0.125f;  // mean over C/G = 8

    const size_t pt = ((size_t)b * NBc + n) * HWc + hw;
    sOut[pt * 8 + j] = s;
    sL[(n * 32 + pix) * 9 + j] = s;
  }
  __syncthreads();

  // fused stats1: y = w0 @ s over this block's 288 points
  float sy[16], sy2[16];
#pragma unroll
  for (int c = 0; c < 16; ++c) { sy[c] = 0.f; sy2[c] = 0.f; }
  for (int p = tid; p < 288; p += 256) {
    float sv[8];
#pragma unroll
    for (int k = 0; k < 8; ++k) sv[k] = sL[p * 9 + k];
#pragma unroll
    for (int c = 0; c < 16; ++c) {
      const float* wr = w0s + c * 8;
      float y = wr[0] * sv[0] + wr[1] * sv[1] + wr[2] * sv[2] + wr[3] * sv[3] +
                wr[4] * sv[4] + wr[5] * sv[5] + wr[6] * sv[6] + wr[7] * sv[7];
      sy[c] += y;
      sy2[c] += y * y;
    }
  }
#pragma unroll
  for (int c = 0; c < 16; ++c) {
    for (int off = 32; off >= 1; off >>= 1) {
      sy[c] += __shfl_xor(sy[c], off);
      sy2[c] += __shfl_xor(sy2[c], off);
    }
  }
  const int wid = tid >> 6;
  if ((tid & 63) == 0) {
#pragma unroll
    for (int c = 0; c < 16; ++c) {
      red[wid * 32 + c] = sy[c];
      red[wid * 32 + 16 + c] = sy2[c];
    }
  }
  __syncthreads();
  if (tid < 32) {
    // transposed layout pT[value][block] for fast parallel finalize
    pT[(size_t)tid * NBLK_S + blockIdx.x] =
        red[tid] + red[32 + tid] + red[64 + tid] + red[96 + tid];
  }
}

// ---------------------------------------------------------------------------
// K2: finalize BN1.  16 blocks, one channel each.
__global__ __launch_bounds__(256) void k_fin1(
    const float* __restrict__ pT, const float* __restrict__ g0,
    const float* __restrict__ b0, float* __restrict__ bn1) {
  __shared__ float red[8];
  const int tid = threadIdx.x;
  const int c = blockIdx.x;  // 0..15
  float sa = 0.f, sb = 0.f;
  for (int i = tid; i < NBLK_S; i += 256) {
    sa += pT[(size_t)c * NBLK_S + i];
    sb += pT[(size_t)(16 + c) * NBLK_S + i];
  }
  for (int off = 32; off >= 1; off >>= 1) {
    sa += __shfl_xor(sa, off);
    sb += __shfl_xor(sb, off);
  }
  if ((tid & 63) == 0) { red[(tid >> 6) * 2] = sa; red[(tid >> 6) * 2 + 1] = sb; }
  __syncthreads();
  if (tid == 0) {
    const float ta = red[0] + red[2] + red[4] + red[6];
    const float tb = red[1] + red[3] + red[5] + red[7];
    const float invN = 1.f / (float)NPT;
    const float mean = ta * invN;
    const float var = tb * invN - mean * mean;
    const float a = g0[c] * rsqrtf(var + EPSV);
    bn1[c] = a;
    bn1[16 + c] = b0[c] - mean * a;
  }
}

// ---------------------------------------------------------------------------
// K3: stats2 partials, z = w1 @ relu(a1*(w0@s)+c1).
__global__ __launch_bounds__(256) void k_stats2(
    const float* __restrict__ sBuf, const float* __restrict__ w0,
    const float* __restrict__ w1, const float* __restrict__ bn1,
    float* __restrict__ p2T) {
  __shared__ float w0s[128], w1s[128], a1s[16], c1s[16];
  __shared__ float red[4 * 16];
  const int tid = threadIdx.x;
  if (tid < 128) { w0s[tid] = w0[tid]; w1s[tid] = w1[tid]; }
  if (tid < 16) { a1s[tid] = bn1[tid]; c1s[tid] = bn1[16 + tid]; }
  __syncthreads();

  float sz[8], sz2[8];
#pragma unroll
  for (int o = 0; o < 8; ++o) { sz[o] = 0.f; sz2[o] = 0.f; }

  const int stride = gridDim.x * blockDim.x;
  for (int p = blockIdx.x * blockDim.x + tid; p < NPT; p += stride) {
    const float4* sp = (const float4*)(sBuf + (size_t)p * 8);
    const float4 s0 = sp[0], s1 = sp[1];
    float x1[16];
#pragma unroll
    for (int c = 0; c < 16; ++c) {
      const float* wr = w0s + c * 8;
      const float y = wr[0] * s0.x + wr[1] * s0.y + wr[2] * s0.z + wr[3] * s0.w +
                      wr[4] * s1.x + wr[5] * s1.y + wr[6] * s1.z + wr[7] * s1.w;
      x1[c] = fmaxf(a1s[c] * y + c1s[c], 0.f);
    }
#pragma unroll
    for (int o = 0; o < 8; ++o) {
      const float* wr = w1s + o * 16;
      float z = 0.f;
#pragma unroll
      for (int k = 0; k < 16; ++k) z += wr[k] * x1[k];
      sz[o] += z;
      sz2[o] += z * z;
    }
  }
#pragma unroll
  for (int o = 0; o < 8; ++o) {
    for (int off = 32; off >= 1; off >>= 1) {
      sz[o] += __shfl_xor(sz[o], off);
      sz2[o] += __shfl_xor(sz2[o], off);
    }
  }
  const int wid = tid >> 6;
  if ((tid & 63) == 0) {
#pragma unroll
    for (int o = 0; o < 8; ++o) {
      red[wid * 16 + o] = sz[o];
      red[wid * 16 + 8 + o] = sz2[o];
    }
  }
  __syncthreads();
  if (tid < 16) {
    p2T[(size_t)tid * NB2 + blockIdx.x] =
        red[tid] + red[16 + tid] + red[32 + tid] + red[48 + tid];
  }
}

// ---------------------------------------------------------------------------
// K4: finalize BN2.  8 blocks, one channel each.
__global__ __launch_bounds__(256) void k_fin2(
    const float* __restrict__ p2T, const float* __restrict__ g1,
    const float* __restrict__ b1, float* __restrict__ bn2) {
  __shared__ float red[8];
  const int tid = threadIdx.x;
  const int c = blockIdx.x;  // 0..7
  float sa = 0.f, sb = 0.f;
  for (int i = tid; i < NB2; i += 256) {
    sa += p2T[(size_t)c * NB2 + i];
    sb += p2T[(size_t)(8 + c) * NB2 + i];
  }
  for (int off = 32; off >= 1; off >>= 1) {
    sa += __shfl_xor(sa, off);
    sb += __shfl_xor(sb, off);
  }
  if ((tid & 63) == 0) { red[(tid >> 6) * 2] = sa; red[(tid >> 6) * 2 + 1] = sb; }
  __syncthreads();
  if (tid == 0) {
    const float ta = red[0] + red[2] + red[4] + red[6];
    const float tb = red[1] + red[3] + red[5] + red[7];
    const float invN = 1.f / (float)NPT;
    const float mean = ta * invN;
    const float var = tb * invN - mean * mean;
    const float a = g1[c] * rsqrtf(var + EPSV);
    bn2[c] = a;
    bn2[8 + c] = b1[c] - mean * a;
  }
}

// ---------------------------------------------------------------------------
// K5: full epilogue: s -> MLP -> sigmoid -> out
__global__ __launch_bounds__(256) void k_final(
    const float* __restrict__ sBuf, const float* __restrict__ w0,
    const float* __restrict__ w1, const float* __restrict__ bn1,
    const float* __restrict__ bn2, const float* __restrict__ wsW,
    const float* __restrict__ bs, float* __restrict__ out) {
  __shared__ float w0s[128], w1s[128], a1s[16], c1s[16], a2s[8], c2s[8], wss[8];
  __shared__ float bss;
  const int tid = threadIdx.x;
  if (tid < 128) { w0s[tid] = w0[tid]; w1s[tid] = w1[tid]; }
  if (tid < 16) { a1s[tid] = bn1[tid]; c1s[tid] = bn1[16 + tid]; }
  if (tid < 8) { a2s[tid] = bn2[tid]; c2s[tid] = bn2[8 + tid]; wss[tid] = wsW[tid]; }
  if (tid == 0) bss = bs[0];
  __syncthreads();

  const int p = blockIdx.x * blockDim.x + tid;
  if (p >= NPT) return;
  const float4* sp = (const float4*)(sBuf + (size_t)p * 8);
  const float4 s0 = sp[0], s1 = sp[1];
  float x1[16];
#pragma unroll
  for (int c = 0; c < 16; ++c) {
    const float* wr = w0s + c * 8;
    const float y = wr[0] * s0.x + wr[1] * s0.y + wr[2] * s0.z + wr[3] * s0.w +
                    wr[4] * s1.x + wr[5] * s1.y + wr[6] * s1.z + wr[7] * s1.w;
    x1[c] = fmaxf(a1s[c] * y + c1s[c], 0.f);
  }
  float o = bss;
#pragma unroll
  for (int oc = 0; oc < 8; ++oc) {
    const float* wr = w1s + oc * 16;
    float z = 0.f;
#pragma unroll
    for (int k = 0; k < 16; ++k) z += wr[k] * x1[k];
    const float x2 = fmaxf(a2s[oc] * z + c2s[oc], 0.f);
    o += wss[oc] * x2;
  }
  out[p] = 1.f / (1.f + expf(-o));
}

// ---------------------------------------------------------------------------
extern "C" void kernel_launch(void* const* d_in, const int* in_sizes, int n_in,
                              void* d_out, int out_size, void* d_ws,
                              size_t ws_size, hipStream_t stream) {
  const float* feat = (const float*)d_in[0];  // [2,64,256,320]
  const float* grid = (const float*)d_in[1];  // [2,2304,320,2]
  const float* w0 = (const float*)d_in[2];    // [16,8]
  const float* g0 = (const float*)d_in[3];
  const float* b0 = (const float*)d_in[4];
  const float* w1 = (const float*)d_in[5];    // [8,16]
  const float* g1 = (const float*)d_in[6];
  const float* b1 = (const float*)d_in[7];
  const float* wsW = (const float*)d_in[8];   // [1,8]
  const float* bs = (const float*)d_in[9];    // [1]
  float* out = (float*)d_out;

  float* wsf = (float*)d_ws;  // ~69 MB
  unsigned short* featB = (unsigned short*)(wsf + OFF_FEATB);
  float* sBuf = wsf + OFF_S;
  float* pT   = wsf + OFF_PT;
  float* bn1  = wsf + OFF_BN1;
  float* p2T  = wsf + OFF_P2T;
  float* bn2  = wsf + OFF_BN2;

  k_transpose<<<Bc * (HWc / 64), 256, 0, stream>>>(feat, featB);
  k_sample<<<NBLK_S, 256, 0, stream>>>(grid, featB, w0, sBuf, pT);
  k_fin1<<<16, 256, 0, stream>>>(pT, g0, b0, bn1);
  k_stats2<<<NB2, 256, 0, stream>>>(sBuf, w0, w1, bn1, p2T);
  k_fin2<<<8, 256, 0, stream>>>(p2T, g1, b1, bn2);
  k_final<<<(NPT + 255) / 256, 256, 0, stream>>>(sBuf, w0, w1, bn1, bn2, wsW, bs, out);
}

// Round 5
// 311.921 us; speedup vs baseline: 1.5563x; 1.5563x over previous
//
#include <hip/hip_runtime.h>
#include <math.h>

// FeatureWeightNet: grid_sample(bilinear,border) -> group correlation (G=8) ->
// MLP(8->16->8->1) with per-batch BN stats -> sigmoid.
// R5: 4 dispatches, spill-free fused stats:
//   k_transpose  NCHW fp32 -> NHWC bf16, zeroes the 88 atomic moment slots
//   k_sample     gather + correlation + s-moment partials (shfl butterfly,
//                9 accumulator regs/lane, atomicAdd to 72 slots)  [R4 lesson:
//                NO wave-min launch_bounds — (256,6) caused scratch spills,
//                FETCH/WRITE +600 MB each]
//   k_stats2     recompute bn1 from moments per block, z/z^2 -> 16 slots
//   k_final      recompute bn1+bn2 per block, MLP + sigmoid -> out

constexpr int   Bc  = 2;
constexpr int   Cc  = 64;
constexpr int   Hc  = 256;
constexpr int   Wc  = 320;
constexpr int   NBc = 9;
constexpr int   HWc = Hc * Wc;            // 81920
constexpr int   NPIX = Bc * HWc;          // 163840
constexpr int   NPT  = Bc * NBc * HWc;    // 1474560 (= out_size)
constexpr float EPSV = 1e-5f;

constexpr int NBLK_S = NPIX / 32;         // 5120 sample blocks
constexpr int NB2    = 1024;              // stats2 blocks

// workspace layout in float units (~45 MB)
constexpr size_t OFF_FEATB = 0;                               // NHWC bf16: NPIX*64 ushort
constexpr size_t OFF_SB    = OFF_FEATB + (size_t)NPIX * 32;   // s bf16: NPT*8 ushort
constexpr size_t OFF_MOM   = OFF_SB + (size_t)NPT * 4;        // 72: m[8], q[8][8]
constexpr size_t OFF_ZM    = OFF_MOM + 72;                    // 16: zsum[8], zsum2[8]

__device__ __forceinline__ unsigned short f2bf_rne(float v) {
  unsigned int u = __float_as_uint(v);
  unsigned int r = (u + 0x7fffu + ((u >> 16) & 1u)) >> 16;
  return (unsigned short)r;
}
__device__ __forceinline__ float bf2f(unsigned short s) {
  return __uint_as_float(((unsigned int)s) << 16);
}
__device__ __forceinline__ void unpack8(uint4 u, float f[8]) {
  f[0] = __uint_as_float(u.x << 16);
  f[1] = __uint_as_float(u.x & 0xffff0000u);
  f[2] = __uint_as_float(u.y << 16);
  f[3] = __uint_as_float(u.y & 0xffff0000u);
  f[4] = __uint_as_float(u.z << 16);
  f[5] = __uint_as_float(u.z & 0xffff0000u);
  f[6] = __uint_as_float(u.w << 16);
  f[7] = __uint_as_float(u.w & 0xffff0000u);
}

// BN1 params for channel c from the 72 moment slots.
// mom[j] = sum s_j ; mom[8 + j*8 + k] = sum s_j * s_{j XOR k}
__device__ __forceinline__ void compute_bn1(
    const float* __restrict__ mom, const float* __restrict__ w0,
    const float* __restrict__ g0, const float* __restrict__ b0, int c,
    float& a_out, float& c_out) {
  const float invN = 1.f / (float)NPT;
  float mu = 0.f, e2 = 0.f;
#pragma unroll
  for (int j = 0; j < 8; ++j) mu += w0[c * 8 + j] * mom[j];
  mu *= invN;
#pragma unroll
  for (int j = 0; j < 8; ++j) {
    float t = 0.f;
#pragma unroll
    for (int l = 0; l < 8; ++l) t += w0[c * 8 + l] * mom[8 + j * 8 + (j ^ l)];
    e2 += w0[c * 8 + j] * t;
  }
  e2 *= invN;
  const float var = e2 - mu * mu;
  a_out = g0[c] * rsqrtf(var + EPSV);
  c_out = b0[c] - mu * a_out;
}

// ---------------------------------------------------------------------------
// K0: NCHW fp32 -> NHWC bf16 transpose; block 0 zeroes the 88 atomic slots.
__global__ __launch_bounds__(256) void k_transpose(
    const float* __restrict__ feat, unsigned short* __restrict__ featB,
    float* __restrict__ mom) {
  if (blockIdx.x == 0 && threadIdx.x < 88) mom[threadIdx.x] = 0.f;
  __shared__ float lds[64][65];
  const int tid  = threadIdx.x;
  const int b    = blockIdx.x / (HWc / 64);
  const int tile = blockIdx.x % (HWc / 64);
  const int hw0  = tile * 64;
  const int p    = tid & 63;
  const int ty   = tid >> 6;  // 0..3

  const float* src = feat + (size_t)b * Cc * HWc + hw0 + p;
#pragma unroll
  for (int c0 = 0; c0 < 64; c0 += 4) {
    lds[c0 + ty][p] = src[(size_t)(c0 + ty) * HWc];
  }
  __syncthreads();
  const int ch = tid & 63;
  unsigned short* dst = featB + ((size_t)b * HWc + hw0) * 64 + ch;
#pragma unroll
  for (int p0 = 0; p0 < 64; p0 += 4) {
    dst[(size_t)(p0 + ty) * 64] = f2bf_rne(lds[ch][p0 + ty]);
  }
}

// ---------------------------------------------------------------------------
// K1: grid sample + group correlation + s-moment partials.
// 8 lanes per pixel; lane j owns group j (16 B bf16 per tap). Block = 32 px.
__global__ __launch_bounds__(256) void k_sample(
    const float* __restrict__ grid, const unsigned short* __restrict__ featB,
    unsigned short* __restrict__ sOut, float* __restrict__ mom) {
  __shared__ float red[4][72];
  const int tid = threadIdx.x;
  const int pix = tid >> 3;                      // 0..31 cluster in block
  const int cid = blockIdx.x * 32 + pix;         // pixel id in [0, NPIX)
  const int j   = tid & 7;                       // group
  const int b   = cid / HWc;
  const int hw  = cid - b * HWc;
  const int h   = hw / Wc;
  const int w   = hw - h * Wc;

  // ref vector (bf16) from own NHWC record: one coalesced uint4 per lane
  const uint4* fbAll = (const uint4*)featB;
  const uint4 ur = fbAll[(size_t)cid * 8 + j];
  float r[8];
  unpack8(ur, r);

  const uint4* fb = fbAll + (size_t)b * HWc * 8;

  float m_acc = 0.f;
  float q[8];
#pragma unroll
  for (int k = 0; k < 8; ++k) q[k] = 0.f;

#pragma unroll 3
  for (int n = 0; n < NBc; ++n) {
    const size_t gi = ((((size_t)b * NBc + n) * Hc + h) * Wc + w) * 2;
    const float2 g2 = *(const float2*)(grid + gi);
    float ix = ((g2.x + 1.f) * (float)Wc - 1.f) * 0.5f;
    float iy = ((g2.y + 1.f) * (float)Hc - 1.f) * 0.5f;
    ix = fminf(fmaxf(ix, 0.f), (float)(Wc - 1));
    iy = fminf(fmaxf(iy, 0.f), (float)(Hc - 1));
    const float x0f = floorf(ix), y0f = floorf(iy);
    const float fx = ix - x0f, fy = iy - y0f;
    const int x0 = (int)x0f, y0 = (int)y0f;
    const int x1 = min(x0 + 1, Wc - 1), y1 = min(y0 + 1, Hc - 1);
    const float w00 = (1.f - fx) * (1.f - fy);
    const float w01 = fx * (1.f - fy);
    const float w10 = (1.f - fx) * fy;
    const float w11 = fx * fy;

    const uint4 u00 = fb[(size_t)(y0 * Wc + x0) * 8 + j];
    const uint4 u01 = fb[(size_t)(y0 * Wc + x1) * 8 + j];
    const uint4 u10 = fb[(size_t)(y1 * Wc + x0) * 8 + j];
    const uint4 u11 = fb[(size_t)(y1 * Wc + x1) * 8 + j];
    float a[8], c[8], d[8], e[8];
    unpack8(u00, a);
    unpack8(u01, c);
    unpack8(u10, d);
    unpack8(u11, e);

    float s = 0.f;
#pragma unroll
    for (int k = 0; k < 8; ++k) {
      s += (w00 * a[k] + w01 * c[k] + w10 * d[k] + w11 * e[k]) * r[k];
    }
    s *= 0.125f;  // mean over C/G = 8

    // round to bf16; store and accumulate the ROUNDED value (consistency
    // between BN1 stats and downstream y computed from the bf16 buffer)
    const unsigned short sb = f2bf_rne(s);
    const size_t pt = ((size_t)b * NBc + n) * HWc + hw;
    sOut[pt * 8 + j] = sb;
    const float sr = bf2f(sb);

    // 8-lane butterfly all-gather: gk = s_{j XOR k}
    const float g0v = sr;
    const float g1v = __shfl_xor(g0v, 1);
    const float g2v = __shfl_xor(g0v, 2);
    const float g3v = __shfl_xor(g1v, 2);
    const float g4v = __shfl_xor(g0v, 4);
    const float g5v = __shfl_xor(g1v, 4);
    const float g6v = __shfl_xor(g2v, 4);
    const float g7v = __shfl_xor(g3v, 4);

    m_acc += sr;
    q[0] += sr * g0v; q[1] += sr * g1v; q[2] += sr * g2v; q[3] += sr * g3v;
    q[4] += sr * g4v; q[5] += sr * g5v; q[6] += sr * g6v; q[7] += sr * g7v;
  }

  // reduce across the 8 clusters of each wave (lanes with equal j)
#pragma unroll
  for (int mask = 8; mask <= 32; mask <<= 1) {
    m_acc += __shfl_xor(m_acc, mask);
#pragma unroll
    for (int k = 0; k < 8; ++k) q[k] += __shfl_xor(q[k], mask);
  }
  const int wv = tid >> 6;
  if ((tid & 63) < 8) {
    red[wv][j] = m_acc;
#pragma unroll
    for (int k = 0; k < 8; ++k) red[wv][8 + j * 8 + k] = q[k];
  }
  __syncthreads();
  if (tid < 72) {
    atomicAdd(&mom[tid], red[0][tid] + red[1][tid] + red[2][tid] + red[3][tid]);
  }
}

// ---------------------------------------------------------------------------
// K2: recompute bn1 from moments; z/z^2 partials -> atomicAdd to zmom[16].
__global__ __launch_bounds__(256) void k_stats2(
    const unsigned short* __restrict__ sB, const float* __restrict__ mom,
    const float* __restrict__ w0, const float* __restrict__ w1,
    const float* __restrict__ g0, const float* __restrict__ b0,
    float* __restrict__ zmom) {
  __shared__ float w0s[128], w1s[128], a1s[16], c1s[16];
  __shared__ float red[4 * 16];
  const int tid = threadIdx.x;
  if (tid < 128) { w0s[tid] = w0[tid]; w1s[tid] = w1[tid]; }
  if (tid < 16) {
    float a, cc;
    compute_bn1(mom, w0, g0, b0, tid, a, cc);
    a1s[tid] = a; c1s[tid] = cc;
  }
  __syncthreads();

  float sz[8], sz2[8];
#pragma unroll
  for (int o = 0; o < 8; ++o) { sz[o] = 0.f; sz2[o] = 0.f; }

  const int stride = gridDim.x * blockDim.x;
  for (int p = blockIdx.x * blockDim.x + tid; p < NPT; p += stride) {
    const uint4 su = ((const uint4*)sB)[p];
    float s[8];
    unpack8(su, s);
    float x1[16];
#pragma unroll
    for (int c = 0; c < 16; ++c) {
      const float* wr = w0s + c * 8;
      float y = 0.f;
#pragma unroll
      for (int k = 0; k < 8; ++k) y += wr[k] * s[k];
      x1[c] = fmaxf(a1s[c] * y + c1s[c], 0.f);
    }
#pragma unroll
    for (int o = 0; o < 8; ++o) {
      const float* wr = w1s + o * 16;
      float z = 0.f;
#pragma unroll
      for (int k = 0; k < 16; ++k) z += wr[k] * x1[k];
      sz[o] += z;
      sz2[o] += z * z;
    }
  }
#pragma unroll
  for (int o = 0; o < 8; ++o) {
    for (int off = 32; off >= 1; off >>= 1) {
      sz[o] += __shfl_xor(sz[o], off);
      sz2[o] += __shfl_xor(sz2[o], off);
    }
  }
  const int wid = tid >> 6;
  if ((tid & 63) == 0) {
#pragma unroll
    for (int o = 0; o < 8; ++o) {
      red[wid * 16 + o] = sz[o];
      red[wid * 16 + 8 + o] = sz2[o];
    }
  }
  __syncthreads();
  if (tid < 16) {
    atomicAdd(&zmom[tid],
              red[tid] + red[16 + tid] + red[32 + tid] + red[48 + tid]);
  }
}

// ---------------------------------------------------------------------------
// K3: recompute bn1 + bn2 per block; full epilogue MLP + sigmoid -> out.
__global__ __launch_bounds__(256) void k_final(
    const unsigned short* __restrict__ sB, const float* __restrict__ mom,
    const float* __restrict__ zmom, const float* __restrict__ w0,
    const float* __restrict__ w1, const float* __restrict__ g0,
    const float* __restrict__ b0, const float* __restrict__ g1,
    const float* __restrict__ b1, const float* __restrict__ wsW,
    const float* __restrict__ bs, float* __restrict__ out) {
  __shared__ float w0s[128], w1s[128], a1s[16], c1s[16], a2s[8], c2s[8], wss[8];
  __shared__ float bss;
  const int tid = threadIdx.x;
  if (tid < 128) { w0s[tid] = w0[tid]; w1s[tid] = w1[tid]; }
  if (tid < 16) {
    float a, cc;
    compute_bn1(mom, w0, g0, b0, tid, a, cc);
    a1s[tid] = a; c1s[tid] = cc;
  }
  if (tid >= 128 && tid < 136) {
    const int o = tid - 128;
    const float invN = 1.f / (float)NPT;
    const float mean = zmom[o] * invN;
    const float var = zmom[8 + o] * invN - mean * mean;
    const float a = g1[o] * rsqrtf(var + EPSV);
    a2s[o] = a;
    c2s[o] = b1[o] - mean * a;
    wss[o] = wsW[o];
  }
  if (tid == 255) bss = bs[0];
  __syncthreads();

  const int p = blockIdx.x * blockDim.x + tid;
  if (p >= NPT) return;
  const uint4 su = ((const uint4*)sB)[p];
  float s[8];
  unpack8(su, s);
  float x1[16];
#pragma unroll
  for (int c = 0; c < 16; ++c) {
    const float* wr = w0s + c * 8;
    float y = 0.f;
#pragma unroll
    for (int k = 0; k < 8; ++k) y += wr[k] * s[k];
    x1[c] = fmaxf(a1s[c] * y + c1s[c], 0.f);
  }
  float o = bss;
#pragma unroll
  for (int oc = 0; oc < 8; ++oc) {
    const float* wr = w1s + oc * 16;
    float z = 0.f;
#pragma unroll
    for (int k = 0; k < 16; ++k) z += wr[k] * x1[k];
    const float x2 = fmaxf(a2s[oc] * z + c2s[oc], 0.f);
    o += wss[oc] * x2;
  }
  out[p] = 1.f / (1.f + expf(-o));
}

// ---------------------------------------------------------------------------
extern "C" void kernel_launch(void* const* d_in, const int* in_sizes, int n_in,
                              void* d_out, int out_size, void* d_ws,
                              size_t ws_size, hipStream_t stream) {
  const float* feat = (const float*)d_in[0];  // [2,64,256,320]
  const float* grid = (const float*)d_in[1];  // [2,2304,320,2]
  const float* w0 = (const float*)d_in[2];    // [16,8]
  const float* g0 = (const float*)d_in[3];
  const float* b0 = (const float*)d_in[4];
  const float* w1 = (const float*)d_in[5];    // [8,16]
  const float* g1 = (const float*)d_in[6];
  const float* b1 = (const float*)d_in[7];
  const float* wsW = (const float*)d_in[8];   // [1,8]
  const float* bs = (const float*)d_in[9];    // [1]
  float* out = (float*)d_out;

  float* wsf = (float*)d_ws;  // ~45 MB
  unsigned short* featB = (unsigned short*)(wsf + OFF_FEATB);
  unsigned short* sB    = (unsigned short*)(wsf + OFF_SB);
  float* mom  = wsf + OFF_MOM;   // 72 slots (+16 zmom contiguous after)
  float* zmom = wsf + OFF_ZM;

  k_transpose<<<Bc * (HWc / 64), 256, 0, stream>>>(feat, featB, mom);
  k_sample<<<NBLK_S, 256, 0, stream>>>(grid, featB, sB, mom);
  k_stats2<<<NB2, 256, 0, stream>>>(sB, mom, w0, w1, g0, b0, zmom);
  k_final<<<(NPT + 255) / 256, 256, 0, stream>>>(sB, mom, zmom, w0, w1, g0, b0,
                                                 g1, b1, wsW, bs, out);
}

// Round 6
// 309.354 us; speedup vs baseline: 1.5692x; 1.0083x over previous
//
#include <hip/hip_runtime.h>
#include <math.h>

// FeatureWeightNet: grid_sample(bilinear,border) -> group correlation (G=8) ->
// MLP(8->16->8->1) with per-batch BN stats -> sigmoid.
// R6: like R5 (4 dispatches, moment-based fused BN1 stats) but k_sample is
// restructured: grid coords prefetched, gather loop is pure memory+FMA with
// s kept in sreg[9], and the moment butterfly (depth-1 independent shfl_xor)
// runs after the loop.  [R5 lesson: chained shfls inside the gather loop
// serialized it and halved achieved BW 3.9->1.9 TB/s]

constexpr int   Bc  = 2;
constexpr int   Cc  = 64;
constexpr int   Hc  = 256;
constexpr int   Wc  = 320;
constexpr int   NBc = 9;
constexpr int   HWc = Hc * Wc;            // 81920
constexpr int   NPIX = Bc * HWc;          // 163840
constexpr int   NPT  = Bc * NBc * HWc;    // 1474560 (= out_size)
constexpr float EPSV = 1e-5f;

constexpr int NBLK_S = NPIX / 32;         // 5120 sample blocks
constexpr int NB2    = 1024;              // stats2 blocks

// workspace layout in float units (~45 MB)
constexpr size_t OFF_FEATB = 0;                               // NHWC bf16: NPIX*64 ushort
constexpr size_t OFF_SB    = OFF_FEATB + (size_t)NPIX * 32;   // s bf16: NPT*8 ushort
constexpr size_t OFF_MOM   = OFF_SB + (size_t)NPT * 4;        // 72: m[8], q[8][8]
constexpr size_t OFF_ZM    = OFF_MOM + 72;                    // 16: zsum[8], zsum2[8]

__device__ __forceinline__ unsigned short f2bf_rne(float v) {
  unsigned int u = __float_as_uint(v);
  unsigned int r = (u + 0x7fffu + ((u >> 16) & 1u)) >> 16;
  return (unsigned short)r;
}
__device__ __forceinline__ float bf2f(unsigned short s) {
  return __uint_as_float(((unsigned int)s) << 16);
}
__device__ __forceinline__ void unpack8(uint4 u, float f[8]) {
  f[0] = __uint_as_float(u.x << 16);
  f[1] = __uint_as_float(u.x & 0xffff0000u);
  f[2] = __uint_as_float(u.y << 16);
  f[3] = __uint_as_float(u.y & 0xffff0000u);
  f[4] = __uint_as_float(u.z << 16);
  f[5] = __uint_as_float(u.z & 0xffff0000u);
  f[6] = __uint_as_float(u.w << 16);
  f[7] = __uint_as_float(u.w & 0xffff0000u);
}

// BN1 params for channel c from the 72 moment slots.
// mom[j] = sum s_j ; mom[8 + j*8 + k] = sum s_j * s_{j XOR k}
__device__ __forceinline__ void compute_bn1(
    const float* __restrict__ mom, const float* __restrict__ w0,
    const float* __restrict__ g0, const float* __restrict__ b0, int c,
    float& a_out, float& c_out) {
  const float invN = 1.f / (float)NPT;
  float mu = 0.f, e2 = 0.f;
#pragma unroll
  for (int j = 0; j < 8; ++j) mu += w0[c * 8 + j] * mom[j];
  mu *= invN;
#pragma unroll
  for (int j = 0; j < 8; ++j) {
    float t = 0.f;
#pragma unroll
    for (int l = 0; l < 8; ++l) t += w0[c * 8 + l] * mom[8 + j * 8 + (j ^ l)];
    e2 += w0[c * 8 + j] * t;
  }
  e2 *= invN;
  const float var = e2 - mu * mu;
  a_out = g0[c] * rsqrtf(var + EPSV);
  c_out = b0[c] - mu * a_out;
}

// ---------------------------------------------------------------------------
// K0: NCHW fp32 -> NHWC bf16 transpose; block 0 zeroes the 88 atomic slots.
__global__ __launch_bounds__(256) void k_transpose(
    const float* __restrict__ feat, unsigned short* __restrict__ featB,
    float* __restrict__ mom) {
  if (blockIdx.x == 0 && threadIdx.x < 88) mom[threadIdx.x] = 0.f;
  __shared__ float lds[64][65];
  const int tid  = threadIdx.x;
  const int b    = blockIdx.x / (HWc / 64);
  const int tile = blockIdx.x % (HWc / 64);
  const int hw0  = tile * 64;
  const int p    = tid & 63;
  const int ty   = tid >> 6;  // 0..3

  const float* src = feat + (size_t)b * Cc * HWc + hw0 + p;
#pragma unroll
  for (int c0 = 0; c0 < 64; c0 += 4) {
    lds[c0 + ty][p] = src[(size_t)(c0 + ty) * HWc];
  }
  __syncthreads();
  const int ch = tid & 63;
  unsigned short* dst = featB + ((size_t)b * HWc + hw0) * 64 + ch;
#pragma unroll
  for (int p0 = 0; p0 < 64; p0 += 4) {
    dst[(size_t)(p0 + ty) * 64] = f2bf_rne(lds[ch][p0 + ty]);
  }
}

// ---------------------------------------------------------------------------
// K1: grid sample + group correlation + s-moment partials.
// 8 lanes per pixel; lane j owns group j (16 B bf16 per tap). Block = 32 px.
__global__ __launch_bounds__(256) void k_sample(
    const float* __restrict__ grid, const unsigned short* __restrict__ featB,
    unsigned short* __restrict__ sOut, float* __restrict__ mom) {
  __shared__ float red[4][72];
  const int tid = threadIdx.x;
  const int pix = tid >> 3;                      // 0..31 cluster in block
  const int cid = blockIdx.x * 32 + pix;         // pixel id in [0, NPIX)
  const int j   = tid & 7;                       // group
  const int b   = cid / HWc;
  const int hw  = cid - b * HWc;
  const int h   = hw / Wc;
  const int w   = hw - h * Wc;

  // prefetch all 9 grid coords (independent loads, all in flight)
  float2 gc[NBc];
#pragma unroll
  for (int n = 0; n < NBc; ++n) {
    gc[n] = *(const float2*)(grid +
            ((((size_t)b * NBc + n) * Hc + h) * Wc + w) * 2);
  }

  // ref vector (bf16) from own NHWC record: one coalesced uint4 per lane
  const uint4* fbAll = (const uint4*)featB;
  const uint4 ur = fbAll[(size_t)cid * 8 + j];
  float r[8];
  unpack8(ur, r);

  const uint4* fb = fbAll + (size_t)b * HWc * 8;

  float sreg[NBc];

  // pure gather loop: loads + FMA + store, no cross-lane ops
#pragma unroll 3
  for (int n = 0; n < NBc; ++n) {
    float ix = ((gc[n].x + 1.f) * (float)Wc - 1.f) * 0.5f;
    float iy = ((gc[n].y + 1.f) * (float)Hc - 1.f) * 0.5f;
    ix = fminf(fmaxf(ix, 0.f), (float)(Wc - 1));
    iy = fminf(fmaxf(iy, 0.f), (float)(Hc - 1));
    const float x0f = floorf(ix), y0f = floorf(iy);
    const float fx = ix - x0f, fy = iy - y0f;
    const int x0 = (int)x0f, y0 = (int)y0f;
    const int x1 = min(x0 + 1, Wc - 1), y1 = min(y0 + 1, Hc - 1);
    const float w00 = (1.f - fx) * (1.f - fy);
    const float w01 = fx * (1.f - fy);
    const float w10 = (1.f - fx) * fy;
    const float w11 = fx * fy;

    const uint4 u00 = fb[(size_t)(y0 * Wc + x0) * 8 + j];
    const uint4 u01 = fb[(size_t)(y0 * Wc + x1) * 8 + j];
    const uint4 u10 = fb[(size_t)(y1 * Wc + x0) * 8 + j];
    const uint4 u11 = fb[(size_t)(y1 * Wc + x1) * 8 + j];
    float a[8], c[8], d[8], e[8];
    unpack8(u00, a);
    unpack8(u01, c);
    unpack8(u10, d);
    unpack8(u11, e);

    float s = 0.f;
#pragma unroll
    for (int k = 0; k < 8; ++k) {
      s += (w00 * a[k] + w01 * c[k] + w10 * d[k] + w11 * e[k]) * r[k];
    }
    s *= 0.125f;  // mean over C/G = 8

    // round to bf16; store and keep the ROUNDED value (BN1 stats consistent
    // with downstream y computed from the bf16 buffer)
    const unsigned short sb = f2bf_rne(s);
    const size_t pt = ((size_t)b * NBc + n) * HWc + hw;
    sOut[pt * 8 + j] = sb;
    sreg[n] = bf2f(sb);
  }

  // moments, off the memory path: depth-1 independent shfl_xor butterfly
  float m_acc = 0.f;
  float q[8];
#pragma unroll
  for (int k = 0; k < 8; ++k) q[k] = 0.f;
#pragma unroll
  for (int n = 0; n < NBc; ++n) {
    const float sr = sreg[n];
    m_acc += sr;
    q[0] += sr * sr;
#pragma unroll
    for (int k = 1; k < 8; ++k) q[k] += sr * __shfl_xor(sr, k);
  }

  // reduce across the 8 clusters of each wave (lanes with equal j)
#pragma unroll
  for (int mask = 8; mask <= 32; mask <<= 1) {
    m_acc += __shfl_xor(m_acc, mask);
#pragma unroll
    for (int k = 0; k < 8; ++k) q[k] += __shfl_xor(q[k], mask);
  }
  const int wv = tid >> 6;
  if ((tid & 63) < 8) {
    red[wv][j] = m_acc;
#pragma unroll
    for (int k = 0; k < 8; ++k) red[wv][8 + j * 8 + k] = q[k];
  }
  __syncthreads();
  if (tid < 72) {
    atomicAdd(&mom[tid], red[0][tid] + red[1][tid] + red[2][tid] + red[3][tid]);
  }
}

// ---------------------------------------------------------------------------
// K2: recompute bn1 from moments; z/z^2 partials -> atomicAdd to zmom[16].
__global__ __launch_bounds__(256) void k_stats2(
    const unsigned short* __restrict__ sB, const float* __restrict__ mom,
    const float* __restrict__ w0, const float* __restrict__ w1,
    const float* __restrict__ g0, const float* __restrict__ b0,
    float* __restrict__ zmom) {
  __shared__ float w0s[128], w1s[128], a1s[16], c1s[16];
  __shared__ float red[4 * 16];
  const int tid = threadIdx.x;
  if (tid < 128) { w0s[tid] = w0[tid]; w1s[tid] = w1[tid]; }
  if (tid < 16) {
    float a, cc;
    compute_bn1(mom, w0, g0, b0, tid, a, cc);
    a1s[tid] = a; c1s[tid] = cc;
  }
  __syncthreads();

  float sz[8], sz2[8];
#pragma unroll
  for (int o = 0; o < 8; ++o) { sz[o] = 0.f; sz2[o] = 0.f; }

  const int stride = gridDim.x * blockDim.x;
  for (int p = blockIdx.x * blockDim.x + tid; p < NPT; p += stride) {
    const uint4 su = ((const uint4*)sB)[p];
    float s[8];
    unpack8(su, s);
    float x1[16];
#pragma unroll
    for (int c = 0; c < 16; ++c) {
      const float* wr = w0s + c * 8;
      float y = 0.f;
#pragma unroll
      for (int k = 0; k < 8; ++k) y += wr[k] * s[k];
      x1[c] = fmaxf(a1s[c] * y + c1s[c], 0.f);
    }
#pragma unroll
    for (int o = 0; o < 8; ++o) {
      const float* wr = w1s + o * 16;
      float z = 0.f;
#pragma unroll
      for (int k = 0; k < 16; ++k) z += wr[k] * x1[k];
      sz[o] += z;
      sz2[o] += z * z;
    }
  }
#pragma unroll
  for (int o = 0; o < 8; ++o) {
    for (int off = 32; off >= 1; off >>= 1) {
      sz[o] += __shfl_xor(sz[o], off);
      sz2[o] += __shfl_xor(sz2[o], off);
    }
  }
  const int wid = tid >> 6;
  if ((tid & 63) == 0) {
#pragma unroll
    for (int o = 0; o < 8; ++o) {
      red[wid * 16 + o] = sz[o];
      red[wid * 16 + 8 + o] = sz2[o];
    }
  }
  __syncthreads();
  if (tid < 16) {
    atomicAdd(&zmom[tid],
              red[tid] + red[16 + tid] + red[32 + tid] + red[48 + tid]);
  }
}

// ---------------------------------------------------------------------------
// K3: recompute bn1 + bn2 per block; full epilogue MLP + sigmoid -> out.
__global__ __launch_bounds__(256) void k_final(
    const unsigned short* __restrict__ sB, const float* __restrict__ mom,
    const float* __restrict__ zmom, const float* __restrict__ w0,
    const float* __restrict__ w1, const float* __restrict__ g0,
    const float* __restrict__ b0, const float* __restrict__ g1,
    const float* __restrict__ b1, const float* __restrict__ wsW,
    const float* __restrict__ bs, float* __restrict__ out) {
  __shared__ float w0s[128], w1s[128], a1s[16], c1s[16], a2s[8], c2s[8], wss[8];
  __shared__ float bss;
  const int tid = threadIdx.x;
  if (tid < 128) { w0s[tid] = w0[tid]; w1s[tid] = w1[tid]; }
  if (tid < 16) {
    float a, cc;
    compute_bn1(mom, w0, g0, b0, tid, a, cc);
    a1s[tid] = a; c1s[tid] = cc;
  }
  if (tid >= 128 && tid < 136) {
    const int o = tid - 128;
    const float invN = 1.f / (float)NPT;
    const float mean = zmom[o] * invN;
    const float var = zmom[8 + o] * invN - mean * mean;
    const float a = g1[o] * rsqrtf(var + EPSV);
    a2s[o] = a;
    c2s[o] = b1[o] - mean * a;
    wss[o] = wsW[o];
  }
  if (tid == 255) bss = bs[0];
  __syncthreads();

  const int p = blockIdx.x * blockDim.x + tid;
  if (p >= NPT) return;
  const uint4 su = ((const uint4*)sB)[p];
  float s[8];
  unpack8(su, s);
  float x1[16];
#pragma unroll
  for (int c = 0; c < 16; ++c) {
    const float* wr = w0s + c * 8;
    float y = 0.f;
#pragma unroll
    for (int k = 0; k < 8; ++k) y += wr[k] * s[k];
    x1[c] = fmaxf(a1s[c] * y + c1s[c], 0.f);
  }
  float o = bss;
#pragma unroll
  for (int oc = 0; oc < 8; ++oc) {
    const float* wr = w1s + oc * 16;
    float z = 0.f;
#pragma unroll
    for (int k = 0; k < 16; ++k) z += wr[k] * x1[k];
    const float x2 = fmaxf(a2s[oc] * z + c2s[oc], 0.f);
    o += wss[oc] * x2;
  }
  out[p] = 1.f / (1.f + expf(-o));
}

// ---------------------------------------------------------------------------
extern "C" void kernel_launch(void* const* d_in, const int* in_sizes, int n_in,
                              void* d_out, int out_size, void* d_ws,
                              size_t ws_size, hipStream_t stream) {
  const float* feat = (const float*)d_in[0];  // [2,64,256,320]
  const float* grid = (const float*)d_in[1];  // [2,2304,320,2]
  const float* w0 = (const float*)d_in[2];    // [16,8]
  const float* g0 = (const float*)d_in[3];
  const float* b0 = (const float*)d_in[4];
  const float* w1 = (const float*)d_in[5];    // [8,16]
  const float* g1 = (const float*)d_in[6];
  const float* b1 = (const float*)d_in[7];
  const float* wsW = (const float*)d_in[8];   // [1,8]
  const float* bs = (const float*)d_in[9];    // [1]
  float* out = (float*)d_out;

  float* wsf = (float*)d_ws;  // ~45 MB
  unsigned short* featB = (unsigned short*)(wsf + OFF_FEATB);
  unsigned short* sB    = (unsigned short*)(wsf + OFF_SB);
  float* mom  = wsf + OFF_MOM;   // 72 slots (+16 zmom contiguous after)
  float* zmom = wsf + OFF_ZM;

  k_transpose<<<Bc * (HWc / 64), 256, 0, stream>>>(feat, featB, mom);
  k_sample<<<NBLK_S, 256, 0, stream>>>(grid, featB, sB, mom);
  k_stats2<<<NB2, 256, 0, stream>>>(sB, mom, w0, w1, g0, b0, zmom);
  k_final<<<(NPT + 255) / 256, 256, 0, stream>>>(sB, mom, zmom, w0, w1, g0, b0,
                                                 g1, b1, wsW, bs, out);
}

// Round 7
// 260.470 us; speedup vs baseline: 1.8637x; 1.1877x over previous
//
#include <hip/hip_runtime.h>
#include <math.h>

// FeatureWeightNet: grid_sample(bilinear,border) -> group correlation (G=8) ->
// MLP(8->16->8->1) with per-batch BN stats -> sigmoid.
// R7: DE-FUSED sample (R2's proven 3.9 TB/s gather structure: no stats tail,
// no LDS, no cross-lane ops — any fused tail tips the register allocator into
// 36-40 VGPR / low-ILP mode, halving achieved BW [R4/R5/R6 evidence]).
// 5 dispatches:
//   k_transpose  NCHW fp32 -> NHWC bf16 (+ zero 48 atomic slots)
//   k_sample     gather + correlation -> bf16 s (pure, R2-clone)
//   k_stats1     y/y^2 sums (streaming 24 MB) -> ymom[32] atomics
//   k_stats2     bn1 inline from ymom; z/z^2 -> zmom[16] atomics
//   k_final      bn1+bn2 inline; MLP + sigmoid -> out

constexpr int   Bc  = 2;
constexpr int   Cc  = 64;
constexpr int   Hc  = 256;
constexpr int   Wc  = 320;
constexpr int   NBc = 9;
constexpr int   HWc = Hc * Wc;            // 81920
constexpr int   NPIX = Bc * HWc;          // 163840
constexpr int   NPT  = Bc * NBc * HWc;    // 1474560 (= out_size)
constexpr float EPSV = 1e-5f;

constexpr int NBLK_S = NPIX / 32;         // 5120 sample blocks
constexpr int NB1    = 1024;              // stats1 blocks
constexpr int NB2    = 1024;              // stats2 blocks

// workspace layout in float units (~45 MB)
constexpr size_t OFF_FEATB = 0;                               // NHWC bf16: NPIX*64 ushort
constexpr size_t OFF_SB    = OFF_FEATB + (size_t)NPIX * 32;   // s bf16: NPT*8 ushort
constexpr size_t OFF_YM    = OFF_SB + (size_t)NPT * 4;        // ymom: sy[16], sy2[16]
constexpr size_t OFF_ZM    = OFF_YM + 32;                     // zmom: zsum[8], zsum2[8]

__device__ __forceinline__ unsigned short f2bf_rne(float v) {
  unsigned int u = __float_as_uint(v);
  unsigned int r = (u + 0x7fffu + ((u >> 16) & 1u)) >> 16;
  return (unsigned short)r;
}
__device__ __forceinline__ void unpack8(uint4 u, float f[8]) {
  f[0] = __uint_as_float(u.x << 16);
  f[1] = __uint_as_float(u.x & 0xffff0000u);
  f[2] = __uint_as_float(u.y << 16);
  f[3] = __uint_as_float(u.y & 0xffff0000u);
  f[4] = __uint_as_float(u.z << 16);
  f[5] = __uint_as_float(u.z & 0xffff0000u);
  f[6] = __uint_as_float(u.w << 16);
  f[7] = __uint_as_float(u.w & 0xffff0000u);
}

// ---------------------------------------------------------------------------
// K0: NCHW fp32 -> NHWC bf16 transpose; block 0 zeroes the 48 atomic slots.
__global__ __launch_bounds__(256) void k_transpose(
    const float* __restrict__ feat, unsigned short* __restrict__ featB,
    float* __restrict__ ymom) {
  if (blockIdx.x == 0 && threadIdx.x < 48) ymom[threadIdx.x] = 0.f;
  __shared__ float lds[64][65];
  const int tid  = threadIdx.x;
  const int b    = blockIdx.x / (HWc / 64);
  const int tile = blockIdx.x % (HWc / 64);
  const int hw0  = tile * 64;
  const int p    = tid & 63;
  const int ty   = tid >> 6;  // 0..3

  const float* src = feat + (size_t)b * Cc * HWc + hw0 + p;
#pragma unroll
  for (int c0 = 0; c0 < 64; c0 += 4) {
    lds[c0 + ty][p] = src[(size_t)(c0 + ty) * HWc];
  }
  __syncthreads();
  const int ch = tid & 63;
  unsigned short* dst = featB + ((size_t)b * HWc + hw0) * 64 + ch;
#pragma unroll
  for (int p0 = 0; p0 < 64; p0 += 4) {
    dst[(size_t)(p0 + ty) * 64] = f2bf_rne(lds[ch][p0 + ty]);
  }
}

// ---------------------------------------------------------------------------
// K1: grid sample + group correlation.  PURE gather kernel (R2 structure —
// proven 3.9 TB/s): 8 lanes per pixel, lane j owns group j, loop over 9
// neighbors, no LDS, no shuffles, no stats.
__global__ __launch_bounds__(256) void k_sample(
    const float* __restrict__ grid, const unsigned short* __restrict__ featB,
    unsigned short* __restrict__ sOut) {
  const int tid = threadIdx.x;
  const int cid = blockIdx.x * 32 + (tid >> 3);  // pixel id in [0, NPIX)
  const int j   = tid & 7;                       // group
  const int b   = cid / HWc;
  const int hw  = cid - b * HWc;
  const int h   = hw / Wc;
  const int w   = hw - h * Wc;

  // ref vector (bf16) from own NHWC record: one coalesced uint4 per lane
  const uint4* fbAll = (const uint4*)featB;
  const uint4 ur = fbAll[(size_t)cid * 8 + j];
  float r[8];
  unpack8(ur, r);

  const uint4* fb = fbAll + (size_t)b * HWc * 8;

#pragma unroll 3
  for (int n = 0; n < NBc; ++n) {
    const size_t gi = ((((size_t)b * NBc + n) * Hc + h) * Wc + w) * 2;
    const float2 g2 = *(const float2*)(grid + gi);
    float ix = ((g2.x + 1.f) * (float)Wc - 1.f) * 0.5f;
    float iy = ((g2.y + 1.f) * (float)Hc - 1.f) * 0.5f;
    ix = fminf(fmaxf(ix, 0.f), (float)(Wc - 1));
    iy = fminf(fmaxf(iy, 0.f), (float)(Hc - 1));
    const float x0f = floorf(ix), y0f = floorf(iy);
    const float fx = ix - x0f, fy = iy - y0f;
    const int x0 = (int)x0f, y0 = (int)y0f;
    const int x1 = min(x0 + 1, Wc - 1), y1 = min(y0 + 1, Hc - 1);
    const float w00 = (1.f - fx) * (1.f - fy);
    const float w01 = fx * (1.f - fy);
    const float w10 = (1.f - fx) * fy;
    const float w11 = fx * fy;

    const uint4 u00 = fb[(size_t)(y0 * Wc + x0) * 8 + j];
    const uint4 u01 = fb[(size_t)(y0 * Wc + x1) * 8 + j];
    const uint4 u10 = fb[(size_t)(y1 * Wc + x0) * 8 + j];
    const uint4 u11 = fb[(size_t)(y1 * Wc + x1) * 8 + j];
    float a[8], c[8], d[8], e[8];
    unpack8(u00, a);
    unpack8(u01, c);
    unpack8(u10, d);
    unpack8(u11, e);

    float s = 0.f;
#pragma unroll
    for (int k = 0; k < 8; ++k) {
      s += (w00 * a[k] + w01 * c[k] + w10 * d[k] + w11 * e[k]) * r[k];
    }
    s *= 0.125f;  // mean over C/G = 8

    const size_t pt = ((size_t)b * NBc + n) * HWc + hw;
    sOut[pt * 8 + j] = f2bf_rne(s);
  }
}

// ---------------------------------------------------------------------------
// K2: stats1 — y/y^2 sums, y = w0 @ s (16 ch), atomicAdd -> ymom[32].
__global__ __launch_bounds__(256) void k_stats1(
    const unsigned short* __restrict__ sB, const float* __restrict__ w0,
    float* __restrict__ ymom) {
  __shared__ float w0s[128];
  __shared__ float red[4 * 32];
  const int tid = threadIdx.x;
  if (tid < 128) w0s[tid] = w0[tid];
  __syncthreads();

  float sy[16], sy2[16];
#pragma unroll
  for (int c = 0; c < 16; ++c) { sy[c] = 0.f; sy2[c] = 0.f; }

  const int stride = gridDim.x * blockDim.x;
  for (int p = blockIdx.x * blockDim.x + tid; p < NPT; p += stride) {
    const uint4 su = ((const uint4*)sB)[p];
    float s[8];
    unpack8(su, s);
#pragma unroll
    for (int c = 0; c < 16; ++c) {
      const float* wr = w0s + c * 8;
      float y = 0.f;
#pragma unroll
      for (int k = 0; k < 8; ++k) y += wr[k] * s[k];
      sy[c] += y;
      sy2[c] += y * y;
    }
  }
#pragma unroll
  for (int c = 0; c < 16; ++c) {
    for (int off = 32; off >= 1; off >>= 1) {
      sy[c] += __shfl_xor(sy[c], off);
      sy2[c] += __shfl_xor(sy2[c], off);
    }
  }
  const int wid = tid >> 6;
  if ((tid & 63) == 0) {
#pragma unroll
    for (int c = 0; c < 16; ++c) {
      red[wid * 32 + c] = sy[c];
      red[wid * 32 + 16 + c] = sy2[c];
    }
  }
  __syncthreads();
  if (tid < 32) {
    atomicAdd(&ymom[tid],
              red[tid] + red[32 + tid] + red[64 + tid] + red[96 + tid]);
  }
}

// ---------------------------------------------------------------------------
// K3: stats2 — bn1 inline from ymom; z/z^2 -> atomicAdd zmom[16].
__global__ __launch_bounds__(256) void k_stats2(
    const unsigned short* __restrict__ sB, const float* __restrict__ ymom,
    const float* __restrict__ w0, const float* __restrict__ w1,
    const float* __restrict__ g0, const float* __restrict__ b0,
    float* __restrict__ zmom) {
  __shared__ float w0s[128], w1s[128], a1s[16], c1s[16];
  __shared__ float red[4 * 16];
  const int tid = threadIdx.x;
  if (tid < 128) { w0s[tid] = w0[tid]; w1s[tid] = w1[tid]; }
  if (tid < 16) {
    const float invN = 1.f / (float)NPT;
    const float mean = ymom[tid] * invN;
    const float var = ymom[16 + tid] * invN - mean * mean;
    const float a = g0[tid] * rsqrtf(var + EPSV);
    a1s[tid] = a;
    c1s[tid] = b0[tid] - mean * a;
  }
  __syncthreads();

  float sz[8], sz2[8];
#pragma unroll
  for (int o = 0; o < 8; ++o) { sz[o] = 0.f; sz2[o] = 0.f; }

  const int stride = gridDim.x * blockDim.x;
  for (int p = blockIdx.x * blockDim.x + tid; p < NPT; p += stride) {
    const uint4 su = ((const uint4*)sB)[p];
    float s[8];
    unpack8(su, s);
    float x1[16];
#pragma unroll
    for (int c = 0; c < 16; ++c) {
      const float* wr = w0s + c * 8;
      float y = 0.f;
#pragma unroll
      for (int k = 0; k < 8; ++k) y += wr[k] * s[k];
      x1[c] = fmaxf(a1s[c] * y + c1s[c], 0.f);
    }
#pragma unroll
    for (int o = 0; o < 8; ++o) {
      const float* wr = w1s + o * 16;
      float z = 0.f;
#pragma unroll
      for (int k = 0; k < 16; ++k) z += wr[k] * x1[k];
      sz[o] += z;
      sz2[o] += z * z;
    }
  }
#pragma unroll
  for (int o = 0; o < 8; ++o) {
    for (int off = 32; off >= 1; off >>= 1) {
      sz[o] += __shfl_xor(sz[o], off);
      sz2[o] += __shfl_xor(sz2[o], off);
    }
  }
  const int wid = tid >> 6;
  if ((tid & 63) == 0) {
#pragma unroll
    for (int o = 0; o < 8; ++o) {
      red[wid * 16 + o] = sz[o];
      red[wid * 16 + 8 + o] = sz2[o];
    }
  }
  __syncthreads();
  if (tid < 16) {
    atomicAdd(&zmom[tid],
              red[tid] + red[16 + tid] + red[32 + tid] + red[48 + tid]);
  }
}

// ---------------------------------------------------------------------------
// K4: final — bn1+bn2 inline; full epilogue MLP + sigmoid -> out.
__global__ __launch_bounds__(256) void k_final(
    const unsigned short* __restrict__ sB, const float* __restrict__ ymom,
    const float* __restrict__ zmom, const float* __restrict__ w0,
    const float* __restrict__ w1, const float* __restrict__ g0,
    const float* __restrict__ b0, const float* __restrict__ g1,
    const float* __restrict__ b1, const float* __restrict__ wsW,
    const float* __restrict__ bs, float* __restrict__ out) {
  __shared__ float w0s[128], w1s[128], a1s[16], c1s[16], a2s[8], c2s[8], wss[8];
  __shared__ float bss;
  const int tid = threadIdx.x;
  if (tid < 128) { w0s[tid] = w0[tid]; w1s[tid] = w1[tid]; }
  if (tid < 16) {
    const float invN = 1.f / (float)NPT;
    const float mean = ymom[tid] * invN;
    const float var = ymom[16 + tid] * invN - mean * mean;
    const float a = g0[tid] * rsqrtf(var + EPSV);
    a1s[tid] = a;
    c1s[tid] = b0[tid] - mean * a;
  }
  if (tid >= 128 && tid < 136) {
    const int o = tid - 128;
    const float invN = 1.f / (float)NPT;
    const float mean = zmom[o] * invN;
    const float var = zmom[8 + o] * invN - mean * mean;
    const float a = g1[o] * rsqrtf(var + EPSV);
    a2s[o] = a;
    c2s[o] = b1[o] - mean * a;
    wss[o] = wsW[o];
  }
  if (tid == 255) bss = bs[0];
  __syncthreads();

  const int p = blockIdx.x * blockDim.x + tid;
  if (p >= NPT) return;
  const uint4 su = ((const uint4*)sB)[p];
  float s[8];
  unpack8(su, s);
  float x1[16];
#pragma unroll
  for (int c = 0; c < 16; ++c) {
    const float* wr = w0s + c * 8;
    float y = 0.f;
#pragma unroll
    for (int k = 0; k < 8; ++k) y += wr[k] * s[k];
    x1[c] = fmaxf(a1s[c] * y + c1s[c], 0.f);
  }
  float o = bss;
#pragma unroll
  for (int oc = 0; oc < 8; ++oc) {
    const float* wr = w1s + oc * 16;
    float z = 0.f;
#pragma unroll
    for (int k = 0; k < 16; ++k) z += wr[k] * x1[k];
    const float x2 = fmaxf(a2s[oc] * z + c2s[oc], 0.f);
    o += wss[oc] * x2;
  }
  out[p] = 1.f / (1.f + expf(-o));
}

// ---------------------------------------------------------------------------
extern "C" void kernel_launch(void* const* d_in, const int* in_sizes, int n_in,
                              void* d_out, int out_size, void* d_ws,
                              size_t ws_size, hipStream_t stream) {
  const float* feat = (const float*)d_in[0];  // [2,64,256,320]
  const float* grid = (const float*)d_in[1];  // [2,2304,320,2]
  const float* w0 = (const float*)d_in[2];    // [16,8]
  const float* g0 = (const float*)d_in[3];
  const float* b0 = (const float*)d_in[4];
  const float* w1 = (const float*)d_in[5];    // [8,16]
  const float* g1 = (const float*)d_in[6];
  const float* b1 = (const float*)d_in[7];
  const float* wsW = (const float*)d_in[8];   // [1,8]
  const float* bs = (const float*)d_in[9];    // [1]
  float* out = (float*)d_out;

  float* wsf = (float*)d_ws;  // ~45 MB
  unsigned short* featB = (unsigned short*)(wsf + OFF_FEATB);
  unsigned short* sB    = (unsigned short*)(wsf + OFF_SB);
  float* ymom = wsf + OFF_YM;   // 32 slots (+16 zmom contiguous after)
  float* zmom = wsf + OFF_ZM;

  k_transpose<<<Bc * (HWc / 64), 256, 0, stream>>>(feat, featB, ymom);
  k_sample<<<NBLK_S, 256, 0, stream>>>(grid, featB, sB);
  k_stats1<<<NB1, 256, 0, stream>>>(sB, w0, ymom);
  k_stats2<<<NB2, 256, 0, stream>>>(sB, ymom, w0, w1, g0, b0, zmom);
  k_final<<<(NPT + 255) / 256, 256, 0, stream>>>(sB, ymom, zmom, w0, w1, g0, b0,
                                                 g1, b1, wsW, bs, out);
}